// Round 4
// baseline (354.698 us; speedup 1.0000x reference)
//
#include <hip/hip_runtime.h>
#include <hip/hip_bf16.h>

#define NPTS 500000
#define NGR  64
#define TR   256
#define NT2  ((NPTS + TR - 1) / TR)   // 1954
#define GRID2 256
#define CHUNK 8                        // ceil(1954/256)

typedef __bf16 bf16x8 __attribute__((ext_vector_type(8)));
typedef float f32x4 __attribute__((ext_vector_type(4)));
typedef unsigned int u32x4 __attribute__((ext_vector_type(4)));

// ---- workspace layout (bytes), all 16B aligned ----
#define OFF_DONE   4096     // u32     : completion counter (k_out fused into k_main)
#define OFF_OUTACC 6144     // u32[8192]: order-preserving max accum
#define OFF_CBIAS  38912    // f32[8192]: per-graph GEMM1 bias row
#define OFF_W1AT   73728    // u16[8192] : bf16 W1[64:128]^T [n=128][k=64], XOR-swizzled
#define OFF_W2T    90112    // u16[16384]: bf16 W2^T [n=128][k=128], XOR-swizzled
#define OFF_W1ET   122880   // u16[4096] : bf16 W1[128:131]^T padded [n=128][k=32], XOR-swizzled
// W1AT|W2T|W1ET are contiguous: one 57344-B region staged to LDS in k_main.

// order-preserving float->u32 map (max over u32 == max over float)
__device__ __forceinline__ unsigned mapf(float f) {
    union { float f; unsigned u; } v; v.f = f;
    return ((int)v.u >= 0) ? (v.u | 0x80000000u) : ~v.u;
}

#define GLOAD_LDS16(g, l) __builtin_amdgcn_global_load_lds(                 \
    (__attribute__((address_space(1))) void*)(g),                           \
    (__attribute__((address_space(3))) void*)(l), 16, 0, 0)

// ---- fused pre-pass (one 1024-thread block per graph):
//      distributed prep (W transposes, outacc/done init) +
//      COM (fp64) + argmin (truncated key) + cbias. No atomics. ----
__global__ __launch_bounds__(1024) void k_pre(
                      const float* __restrict__ pos,
                      const int* __restrict__ batch,
                      const float* __restrict__ x,
                      const float* __restrict__ W1,
                      const float* __restrict__ b1,
                      const float* __restrict__ W2,
                      const float* __restrict__ lfr,
                      unsigned short* __restrict__ W1aT,
                      unsigned short* __restrict__ W2T,
                      unsigned short* __restrict__ W1eT,
                      unsigned* __restrict__ outacc,
                      unsigned* __restrict__ done,
                      float* __restrict__ cbias,
                      float* __restrict__ outf) {
    __shared__ double sd[16][3];
    __shared__ unsigned long long sk[16];
    __shared__ double scom[3];
    __shared__ int sid;
    __shared__ float sposd[3];
    __shared__ float sp[4][128];
    __shared__ int sse[2];

    int g = blockIdx.x, t = threadIdx.x;
    int lane = t & 63, wv = t >> 6;   // wv 0..15

    // ---- distributed prep: 64*1024 = 65536 threads cover all items ----
    {
        int i = g * 1024 + t;
        if (i == 0) *done = 0u;
        if (i < 8192) {
            outacc[i] = 0u;
            int n = i >> 6, k = i & 63;
            unsigned short v = (unsigned short)(__builtin_bit_cast(unsigned, (float)(__bf16)W1[(64 + k) * 128 + n]) >> 16);
            W1aT[i ^ ((n & 7) << 3)] = v;
        } else if (i < 8192 + 16384) {
            int j = i - 8192; int n = j >> 7, k = j & 127;
            unsigned short v = (unsigned short)(__builtin_bit_cast(unsigned, (float)(__bf16)W2[k * 128 + n]) >> 16);
            W2T[j ^ ((n & 7) << 3)] = v;
        } else if (i < 8192 + 16384 + 4096) {
            int j = i - 24576; int n = j >> 5, k = j & 31;
            unsigned short v = 0;
            if (k < 3) v = (unsigned short)(__builtin_bit_cast(unsigned, (float)(__bf16)W1[(128 + k) * 128 + n]) >> 16);
            W1eT[j ^ ((n & 3) << 3)] = v;   // row is 32 shorts: XOR must stay in-row
        }
    }

    // ---- own-range binary search (batch is sorted) ----
    if (t < 2) {
        int target = g + t;
        int lo = 0, hi = NPTS;
        while (lo < hi) {
            int mid = (lo + hi) >> 1;
            if (batch[mid] < target) lo = mid + 1; else hi = mid;
        }
        sse[t] = lo;
    }
    __syncthreads();
    int s = sse[0], e = sse[1];

    // pass 1: fp64 position sums
    double sx = 0.0, sy = 0.0, sz = 0.0;
    for (int i = s + t; i < e; i += 1024) {
        sx += (double)pos[i * 3 + 0];
        sy += (double)pos[i * 3 + 1];
        sz += (double)pos[i * 3 + 2];
    }
    #pragma unroll
    for (int m = 1; m < 64; m <<= 1) {
        sx += __shfl_xor(sx, m);
        sy += __shfl_xor(sy, m);
        sz += __shfl_xor(sz, m);
    }
    if (lane == 0) { sd[wv][0] = sx; sd[wv][1] = sy; sd[wv][2] = sz; }
    __syncthreads();
    if (t == 0) {
        double ax = 0.0, ay = 0.0, az = 0.0;
        for (int q = 0; q < 16; ++q) { ax += sd[q][0]; ay += sd[q][1]; az += sd[q][2]; }
        double cnt = (double)(e - s);
        double rc = 1.0 / (cnt > 1.0 ? cnt : 1.0);
        scom[0] = ax * rc; scom[1] = ay * rc; scom[2] = az * rc;
    }
    __syncthreads();
    double cx = scom[0], cy = scom[1], cz = scom[2];

    // pass 2: argmin of fp64 d2, key = (trunc d2-bits) | id
    unsigned long long key = ~0ULL;
    for (int i = s + t; i < e; i += 1024) {
        double dx = (double)pos[i * 3 + 0] - cx;
        double dy = (double)pos[i * 3 + 1] - cy;
        double dz = (double)pos[i * 3 + 2] - cz;
        double d2 = __builtin_fma(dx, dx, __builtin_fma(dy, dy, dz * dz));
        unsigned long long b = __builtin_bit_cast(unsigned long long, d2);
        unsigned long long k2 = (b & ~0xFFFFFULL) | (unsigned long long)i;
        key = k2 < key ? k2 : key;
    }
    #pragma unroll
    for (int m = 1; m < 64; m <<= 1) {
        unsigned long long o = __shfl_xor(key, m);
        key = o < key ? o : key;
    }
    if (lane == 0) sk[wv] = key;
    __syncthreads();
    if (t == 0) {
        unsigned long long k = sk[0];
        for (int q = 1; q < 16; ++q) if (sk[q] < k) k = sk[q];
        int id = (int)(k & 0xFFFFFULL);
        if (id > NPTS - 1) id = NPTS - 1;
        sid = id;
    }
    __syncthreads();
    int id = sid;

    if (t < 3) {
        float p = pos[id * 3 + t];
        sposd[t] = p;
        outf[8192 + g * 3 + t] = p;
    }
    if (t == 4) outf[8192 + 192 + g] = (float)batch[id];
    if (t < 9) outf[8192 + 256 + g * 9 + t] = lfr[id * 9 + t];

    // cbias: 4-way split over k, then ordered combine
    if (t < 512) {
        int c = t & 127, p = t >> 7;
        float part = 0.f;
        #pragma unroll
        for (int kq = 0; kq < 16; ++kq) {
            int k = p * 16 + kq;
            float xd = x[id * 64 + k];
            part += xd * (W1[k * 128 + c] - W1[(64 + k) * 128 + c]);
        }
        sp[p][c] = part;
    }
    __syncthreads();
    if (t < 128) {
        int c = t;
        float sv = b1[c] + sp[0][c] + sp[1][c] + sp[2][c] + sp[3][c];
        sv -= sposd[0] * W1[128 * 128 + c] + sposd[1] * W1[129 * 128 + c] + sposd[2] * W1[130 * 128 + c];
        cbias[g * 128 + c] = sv;
    }
}

// ---- main: 1024 threads = 16 waves x M=16 rows (tile 256 rows).
//      W staged once in LDS (swizzled, conflict-free); h in wave-private
//      [16][132] stripe; zero barriers in the loop; next-tile x prefetch.
//      M=16 keeps acc/acc2 at 32 VGPRs each -> fits the 128-VGPR budget
//      for 4 waves/SIMD ((512,2)-class caps spilled at M=32, see r2/r3). ----
__global__ __launch_bounds__(1024, 1) void k_main(
    const float* __restrict__ x,
    const float* __restrict__ pos,
    const int* __restrict__ batch,
    const unsigned short* __restrict__ W1aT,   // base of contiguous W region
    const float* __restrict__ cbias,
    unsigned* __restrict__ outacc,
    unsigned* __restrict__ done,
    const float* __restrict__ b2v,
    float* __restrict__ outf)
{
    // [0,16384): W1aT  [16384,49152): W2T  [49152,57344): W1eT
    // [57344,124928): h stripes 16 x [16][132] bf16 (4224 B each)
    __shared__ alignas(16) unsigned char smem[124928];
    __shared__ unsigned sflag;

    const int tid  = threadIdx.x;        // 0..1023
    const int w    = tid >> 6;           // 0..15
    const int lane = tid & 63;
    const int quad = lane >> 4;
    const int mr   = lane & 15;

    // stage all W tables (57344 B = 3584 x 16B, contiguous in ws)
    #pragma unroll
    for (int i = 0; i < 4; ++i) {
        int c = i * 1024 + tid;
        if (c < 3584)
            GLOAD_LDS16((const char*)W1aT + c * 16, (char*)smem + c * 16);
    }
    __syncthreads();   // the only block-wide barrier before the tail

    const unsigned short* sW1 = (const unsigned short*)smem;          // [128][64]
    const unsigned short* sW2 = sW1 + 8192;                            // [128][128]
    const unsigned short* sWe = sW1 + 24576;                           // [128][32]
    __bf16* hsb = (__bf16*)(smem + 57344) + w * 2112;                  // [16][132]
    const unsigned short* hss = (const unsigned short*)hsb;

    int tb = blockIdx.x * CHUNK;
    int te = tb + CHUNK; if (te > NT2) te = NT2;

    // prefetch first tile's A rows (this wave's 16 rows, 256 B each)
    f32x4 av[4];
    if (tb < te) {
        int gr = tb * TR + 16 * w + mr; if (gr > NPTS - 1) gr = NPTS - 1;
        const float* xp = x + (size_t)gr * 64 + quad * 8;
        av[0] = *(const f32x4*)(xp);
        av[1] = *(const f32x4*)(xp + 4);
        av[2] = *(const f32x4*)(xp + 32);
        av[3] = *(const f32x4*)(xp + 36);
    }

    for (int t = tb; t < te; ++t) {
        const int row0 = t * TR + 16 * w;   // this wave's 16 global rows

        // ---- A fragments from prefetched av ----
        bf16x8 afr0, afr1;
        {
            f32x4 va = av[0], vb = av[1], vc = av[2], vd = av[3];
            afr0[0] = (__bf16)va[0]; afr0[1] = (__bf16)va[1]; afr0[2] = (__bf16)va[2]; afr0[3] = (__bf16)va[3];
            afr0[4] = (__bf16)vb[0]; afr0[5] = (__bf16)vb[1]; afr0[6] = (__bf16)vb[2]; afr0[7] = (__bf16)vb[3];
            afr1[0] = (__bf16)vc[0]; afr1[1] = (__bf16)vc[1]; afr1[2] = (__bf16)vc[2]; afr1[3] = (__bf16)vc[3];
            afr1[4] = (__bf16)vd[0]; afr1[5] = (__bf16)vd[1]; afr1[6] = (__bf16)vd[2]; afr1[7] = (__bf16)vd[3];
        }
        // ---- prefetch next tile's A (in flight across both GEMMs) ----
        if (t + 1 < te) {
            int gr = (t + 1) * TR + 16 * w + mr; if (gr > NPTS - 1) gr = NPTS - 1;
            const float* xp = x + (size_t)gr * 64 + quad * 8;
            av[0] = *(const f32x4*)(xp);
            av[1] = *(const f32x4*)(xp + 4);
            av[2] = *(const f32x4*)(xp + 32);
            av[3] = *(const f32x4*)(xp + 36);
        }

        // ---- per-tile meta ----
        int rowg[4]; bool rowv[4];
        #pragma unroll
        for (int r = 0; r < 4; ++r) {
            int gr = row0 + quad * 4 + r;
            rowv[r] = (gr < NPTS);
            rowg[r] = batch[gr < NPTS ? gr : NPTS - 1];
        }
        int gf = batch[row0 < NPTS ? row0 : NPTS - 1];
        int rl = row0 + 15; if (rl > NPTS - 1) rl = NPTS - 1;
        int gl = batch[rl];
        float cb0[8];
        #pragma unroll
        for (int t8 = 0; t8 < 8; ++t8) cb0[t8] = cbias[gf * 128 + t8 * 16 + mr];
        // A-ext fragment: pos of this lane's row in k-slots 0..2 (quad 0 only)
        bf16x8 aE = (bf16x8){0, 0, 0, 0, 0, 0, 0, 0};
        {
            int gp = row0 + mr; if (gp > NPTS - 1) gp = NPTS - 1;
            if (quad == 0) {
                aE[0] = (__bf16)pos[gp * 3 + 0];
                aE[1] = (__bf16)pos[gp * 3 + 1];
                aE[2] = (__bf16)pos[gp * 3 + 2];
            }
        }

        // ---- GEMM1: x.W1a (K=64) + pos.W1e (K-ext, zero-padded) ----
        f32x4 acc[8];
        #pragma unroll
        for (int t8 = 0; t8 < 8; ++t8) acc[t8] = (f32x4){0.f, 0.f, 0.f, 0.f};
        #pragma unroll
        for (int t8 = 0; t8 < 8; ++t8) {
            int n = t8 * 16 + mr;
            int sw = (n & 7) << 3;
            bf16x8 bv0 = __builtin_bit_cast(bf16x8, *(const u32x4*)(sW1 + ((n * 64 + quad * 8) ^ sw)));
            bf16x8 bv1 = __builtin_bit_cast(bf16x8, *(const u32x4*)(sW1 + ((n * 64 + 32 + quad * 8) ^ sw)));
            bf16x8 bve = __builtin_bit_cast(bf16x8, *(const u32x4*)(sWe + ((n * 32 + quad * 8) ^ ((n & 3) << 3))));
            acc[t8] = __builtin_amdgcn_mfma_f32_16x16x32_bf16(afr0, bv0, acc[t8], 0, 0, 0);
            acc[t8] = __builtin_amdgcn_mfma_f32_16x16x32_bf16(afr1, bv1, acc[t8], 0, 0, 0);
            acc[t8] = __builtin_amdgcn_mfma_f32_16x16x32_bf16(aE,   bve, acc[t8], 0, 0, 0);
        }

        // ---- epilogue1: h = relu(acc + cbias[g]) -> wave-private LDS stripe ----
        #pragma unroll
        for (int r = 0; r < 4; ++r) {
            int lrow = quad * 4 + r;
            int g = rowg[r];
            bool odd = (g != gf);
            #pragma unroll
            for (int t8 = 0; t8 < 8; ++t8) {
                float cbv = cb0[t8];
                if (odd) cbv = cbias[g * 128 + t8 * 16 + mr];
                float v = fmaxf(acc[t8][r] + cbv, 0.f);
                hsb[lrow * 132 + t8 * 16 + mr] = (__bf16)v;
            }
        }
        // no barrier: GEMM2 reads only this wave's own stripe (same-wave RAW)

        // ---- GEMM2: h.W2 ----
        f32x4 acc2[8];
        #pragma unroll
        for (int t8 = 0; t8 < 8; ++t8) acc2[t8] = (f32x4){0.f, 0.f, 0.f, 0.f};
        #pragma unroll
        for (int kk = 0; kk < 4; ++kk) {
            bf16x8 a2 = __builtin_bit_cast(bf16x8, *(const u32x4*)(hss + mr * 132 + kk * 32 + quad * 8));
            #pragma unroll
            for (int t8 = 0; t8 < 8; ++t8) {
                int n = t8 * 16 + mr;
                bf16x8 bv = __builtin_bit_cast(bf16x8, *(const u32x4*)(sW2 + ((n * 128 + kk * 32 + quad * 8) ^ ((n & 7) << 3))));
                acc2[t8] = __builtin_amdgcn_mfma_f32_16x16x32_bf16(a2, bv, acc2[t8], 0, 0, 0);
            }
        }

        // ---- epilogue2: per-graph column max -> global atomicMax ----
        for (int g = gf; g <= gl; ++g) {
            #pragma unroll
            for (int t8 = 0; t8 < 8; ++t8) {
                float m = -INFINITY;
                #pragma unroll
                for (int r = 0; r < 4; ++r)
                    if (rowv[r] && rowg[r] == g) m = fmaxf(m, acc2[t8][r]);
                m = fmaxf(m, __shfl_xor(m, 16));
                m = fmaxf(m, __shfl_xor(m, 32));
                if (quad == 0 && __builtin_bit_cast(unsigned, m) != 0xFF800000u)
                    atomicMax(&outacc[g * 128 + t8 * 16 + mr], mapf(m));
            }
        }
    }

    // ---- fused k_out: last block to finish converts outacc -> outf ----
    __threadfence();
    __syncthreads();
    if (tid == 0) sflag = atomicAdd(done, 1u);
    __syncthreads();
    if (sflag == (unsigned)(gridDim.x - 1)) {
        for (int i = tid; i < 8192; i += 1024) {
            unsigned key = atomicMax(&outacc[i], 0u);   // device-scope read
            float v;
            if (key == 0u) {
                v = -300.f;   // diagnostic: never updated
            } else {
                unsigned bits = (key & 0x80000000u) ? (key & 0x7FFFFFFFu) : ~key;
                union { unsigned u; float f; } c; c.u = bits; v = c.f;
            }
            outf[i] = v + b2v[i & 127];
        }
    }
}

extern "C" void kernel_launch(void* const* d_in, const int* in_sizes, int n_in,
                              void* d_out, int out_size, void* d_ws, size_t ws_size,
                              hipStream_t stream) {
    const float* x   = (const float*)d_in[0];
    const float* pos = (const float*)d_in[1];
    const int*   bat = (const int*)d_in[2];
    const float* lfr = (const float*)d_in[3];
    const float* W1  = (const float*)d_in[4];
    const float* b1  = (const float*)d_in[5];
    const float* W2  = (const float*)d_in[6];
    const float* b2v = (const float*)d_in[7];
    float* outf = (float*)d_out;

    char* ws = (char*)d_ws;
    unsigned*       done   = (unsigned*)(ws + OFF_DONE);
    unsigned*       outacc = (unsigned*)(ws + OFF_OUTACC);
    float*          cbias  = (float*)(ws + OFF_CBIAS);
    unsigned short* W1aT   = (unsigned short*)(ws + OFF_W1AT);
    unsigned short* W2T    = (unsigned short*)(ws + OFF_W2T);
    unsigned short* W1eT   = (unsigned short*)(ws + OFF_W1ET);

    k_pre<<<64, 1024, 0, stream>>>(pos, bat, x, W1, b1, W2, lfr,
                                   W1aT, W2T, W1eT, outacc, done, cbias, outf);
    k_main<<<GRID2, 1024, 0, stream>>>(x, pos, bat, W1aT, cbias, outacc, done, b2v, outf);
}